// Round 13
// baseline (2491.875 us; speedup 1.0000x reference)
//
#include <hip/hip_runtime.h>
#include <math.h>

#define NT 256
#define FMA4(acc,u,bv) {acc.x+=(u)*(bv).x; acc.y+=(u)*(bv).y; acc.z+=(u)*(bv).z; acc.w+=(u)*(bv).w;}

__device__ __forceinline__ float sigf(float x){ return 1.0f/(1.0f+expf(-x)); }
__device__ __forceinline__ float rdlane(float v, int l){
  return __int_as_float(__builtin_amdgcn_readlane(__float_as_int(v), l));
}
__device__ __forceinline__ float dot4(float4 a, float4 b){
  return a.x*b.x + a.y*b.y + a.z*b.z + a.w*b.w;
}

__launch_bounds__(NT, 1)
__global__ void kf_fwd(const float* __restrict__ a_seq, const float* __restrict__ h_obs,
  const float* __restrict__ Amat, const float* __restrict__ Cmat, const float* __restrict__ Bmat,
  const float* __restrict__ u_seq, const float* __restrict__ mask, const float* __restrict__ P0,
  const float* __restrict__ matQ, const float* __restrict__ matR,
  const float* __restrict__ Wx, const float* __restrict__ Wh, const float* __restrict__ gbias,
  const float* __restrict__ outW, const float* __restrict__ outb, float* __restrict__ out)
{
  constexpr int T=256, B=128;
  constexpr int L6=36, L0=20;
  constexpr size_t BT=(size_t)B*T;
  const size_t off_zf=0;
  const size_t off_Pf=off_zf+BT*32;
  const size_t off_zl=off_Pf+BT*1024;
  const size_t off_tr=off_zl+BT*32;
  const size_t off_zp=off_tr+BT*1024;
  const size_t off_Pp=off_zp+BT*32;
  const size_t off_af=off_Pp+BT*1024;
  const size_t off_ap=off_af+BT*16;
  const size_t off_S =off_ap+BT*16;
  const size_t off_al=off_S +BT*256;
  const size_t off_ai=off_al+BT*8;
  const size_t off_R =off_ai+BT*8;
  const size_t off_Q =off_R +256;

  __shared__ __align__(16) float sA[8*32*L6];
  __shared__ __align__(16) float sC[8*16*L6];
  __shared__ __align__(16) float W12[48*192];
  __shared__ __align__(16) float gxh[192];
  __shared__ __align__(16) float sBm[1024];
  __shared__ __align__(16) float souWT[512];
  __shared__ __align__(16) float soutb8[8];
  __shared__ __align__(16) float P[32*L6], T1m[32*L6], T3m[32*L6], Qm[32*L6];
  __shared__ __align__(16) float Ak2[2][32*L6];
  __shared__ __align__(16) float Ck2[2][16*L6];
  __shared__ __align__(16) float CPm[16*L6];
  __shared__ __align__(16) float Kg[32*L0];
  __shared__ __align__(16) float Sm[16*L0], Rm[16*L0], Sinv[16*L0];
  __shared__ __align__(16) float LinvT[16*L0];
  __shared__ __align__(16) float Bk[128];
  __shared__ __align__(16) float zj[256], aj[128];
  __shared__ __align__(16) float gx[192], ghl[192];
  __shared__ __align__(16) float zc[32], znew[32], zloc[32], zpred[32], ghs[64];
  __shared__ __align__(16) float aprevv[16], hob[16];
  __shared__ __align__(16) float ak[16], uk[4], rk[16], alpha8[8];
  __shared__ __align__(16) float ys[16], ws[16];
  __shared__ float mvs2[2];

  const int tid  = threadIdx.x;
  const int wid  = tid>>6;
  const int lane = tid&63;
  const int b = blockIdx.x;

  // ---------- init ----------
  for (int e=tid; e<8192; e+=NT){ int k=e>>10, i=(e>>5)&31, j=e&31; sA[(k*32+i)*L6+j]=Amat[e]; }
  for (int e=tid; e<4096; e+=NT){ int k=e>>9, a=(e>>5)&15, i=e&31; sC[(k*16+a)*L6+i]=Cmat[e]; }
  for (int e=tid; e<1024; e+=NT) sBm[e]=Bmat[e];
  for (int e=tid; e<512; e+=NT){ int r=e>>6, q=e&63; souWT[r*64+q]=outW[q*8+r]; }
  if (tid<8) soutb8[tid]=outb[tid];
  for (int e=tid; e<1024; e+=NT){
    int i=e>>5, j=e&31;
    float s=0.f;
    #pragma unroll 8
    for (int k=0;k<32;k++) s += matQ[i*32+k]*matQ[j*32+k];
    Qm[i*L6+j]=s+(i==j?0.001f:0.f);
    P[i*L6+j]=P0[e];
  }
  for (int e=tid; e<256; e+=NT){
    int i=e>>4, j=e&15;
    float s=0.f;
    #pragma unroll
    for (int k=0;k<16;k++) s += matR[i*16+k]*matR[j*16+k];
    Rm[i*L0+j]=s+(i==j?0.001f:0.f);
  }
  for (int e=tid; e<16*L6; e+=NT){ Ck2[0][e]=0.f; Ck2[1][e]=0.f; }
  if (tid<32) zc[tid]=0.f;
  if (tid<64) ghs[tid]=0.f;
  for (int e=tid; e<192; e+=NT) ghl[e]=0.f;
  if (tid<16) hob[tid]=h_obs[b*16+tid];
  __syncthreads();

  // W1 rows + gxh
  if (tid<48){
    const int c0=tid*4;
    #pragma unroll
    for (int a=0;a<16;a++)
      *(float4*)&W12[(32+a)*192+c0] = *(const float4*)(Wx+(size_t)a*192+c0);
    float4 acc=*(const float4*)(gbias+c0);
    #pragma unroll
    for (int i=0;i<16;i++){
      float4 w=*(const float4*)(Wx+(size_t)(16+i)*192+c0);
      float hv=hob[i];
      FMA4(acc,hv,w);
    }
    *(float4*)&gxh[c0]=acc;
  }
  // W2 = Wx[32:64] + M,  M = sum_k CA_k^T @ Wx[64+16k : 80+16k]
  for (int ic=0; ic<4; ++ic){
    float4 Mi[8];
    if (tid<48){
      const int c0=tid*4;
      #pragma unroll
      for (int ii=0;ii<8;ii++)
        Mi[ii]=*(const float4*)(Wx+(size_t)(32+ic*8+ii)*192+c0);
    }
    for (int k=0;k<8;k++){
      __syncthreads();
      if (tid<128){
        int e=tid; int a=e>>3, ii=e&7; int i=ic*8+ii;
        float s=0.f;
        #pragma unroll 8
        for (int j=0;j<32;j++) s+=sC[(k*16+a)*L6+j]*sA[(k*32+j)*L6+i];
        Kg[a*8+ii]=s;
      }
      __syncthreads();
      if (tid<48){
        const int c0=tid*4;
        #pragma unroll
        for (int a=0;a<16;a++){
          float4 w=*(const float4*)(Wx+(size_t)(64+16*k+a)*192+c0);
          #pragma unroll
          for (int ii=0;ii<8;ii++){
            float ca=Kg[a*8+ii];
            FMA4(Mi[ii],ca,w);
          }
        }
      }
    }
    if (tid<48){
      const int c0=tid*4;
      #pragma unroll
      for (int ii=0;ii<8;ii++)
        *(float4*)&W12[(ic*8+ii)*192+c0]=Mi[ii];
    }
  }
  if (b==0){
    for (int e=tid;e<256;e+=NT) out[off_R+e]=Rm[(e>>4)*L0+(e&15)];
    for (int e=tid;e<1024;e+=NT) out[off_Q+e]=Qm[(e>>5)*L6+(e&31)];
  }
  __syncthreads();

  for (int t=0;t<T;t++){
    const size_t bt=(size_t)b*T+t;
    const int pc=t&1, pp=pc^1;

    // ===== Phase A =====
    if (wid==0){
      // head(t): aprev -> gx -> gates -> logits -> alpha -> Ck(t) blend (in-wave)
      if (lane==0) mvs2[pc]=mask[bt];
      float4 zq[8];
      #pragma unroll
      for (int q=0;q<8;q++) zq[q]=*(const float4*)&zc[q*4];
      if (lane<16){
        float s=0.f;
        #pragma unroll
        for (int q=0;q<8;q++) s+=dot4(*(const float4*)&Ck2[pp][lane*L6+q*4], zq[q]);
        aprevv[lane]=s;
      }
      if (lane<48){
        const int c0=lane*4;
        float4 A0=*(const float4*)&gxh[c0];
        float4 A1=make_float4(0.f,0.f,0.f,0.f), A2=A1, A3=A1;
        #pragma unroll
        for (int q=0;q<8;q++){
          float4 zv=zq[q];
          float4 w0=*(const float4*)&W12[(q*4+0)*192+c0];
          float4 w1=*(const float4*)&W12[(q*4+1)*192+c0];
          float4 w2=*(const float4*)&W12[(q*4+2)*192+c0];
          float4 w3=*(const float4*)&W12[(q*4+3)*192+c0];
          FMA4(A0,zv.x,w0); FMA4(A1,zv.y,w1); FMA4(A2,zv.z,w2); FMA4(A3,zv.w,w3);
        }
        #pragma unroll
        for (int q=0;q<4;q++){
          float4 av=*(const float4*)&aprevv[q*4];
          float4 w0=*(const float4*)&W12[(32+q*4+0)*192+c0];
          float4 w1=*(const float4*)&W12[(32+q*4+1)*192+c0];
          float4 w2=*(const float4*)&W12[(32+q*4+2)*192+c0];
          float4 w3=*(const float4*)&W12[(32+q*4+3)*192+c0];
          FMA4(A0,av.x,w0); FMA4(A1,av.y,w1); FMA4(A2,av.z,w2); FMA4(A3,av.w,w3);
        }
        float4 g=make_float4(A0.x+A1.x+A2.x+A3.x, A0.y+A1.y+A2.y+A3.y,
                             A0.z+A1.z+A2.z+A3.z, A0.w+A1.w+A2.w+A3.w);
        *(float4*)&gx[c0]=g;
      }
      {
        float r =sigf(gx[lane]+ghl[lane]);
        float zg=sigf(gx[64+lane]+ghl[64+lane]);
        float n =tanhf(gx[128+lane]+r*ghl[128+lane]);
        float h=ghs[lane];
        ghs[lane]=(1.f-zg)*n+zg*h;
      }
      if (lane<8){
        float s=soutb8[lane];
        #pragma unroll
        for (int q=0;q<16;q++){
          float4 g=*(const float4*)&ghs[q*4];
          float4 w=*(const float4*)&souWT[lane*64+q*4];
          s+=dot4(g,w);
        }
        float m8=s;
        m8=fmaxf(m8,__shfl_xor(m8,1)); m8=fmaxf(m8,__shfl_xor(m8,2)); m8=fmaxf(m8,__shfl_xor(m8,4));
        float e2=expf(s-m8);
        float ss=e2;
        ss+=__shfl_xor(ss,1); ss+=__shfl_xor(ss,2); ss+=__shfl_xor(ss,4);
        float av=e2/ss;
        alpha8[lane]=av;
        out[off_al+bt*8+lane]=av;
      }
      // Ck(t) blend (reads alpha8 written in-wave above)
      {
        float alr[8];
        float4 a0v=*(const float4*)&alpha8[0], a1v=*(const float4*)&alpha8[4];
        alr[0]=a0v.x; alr[1]=a0v.y; alr[2]=a0v.z; alr[3]=a0v.w;
        alr[4]=a1v.x; alr[5]=a1v.y; alr[6]=a1v.z; alr[7]=a1v.w;
        #pragma unroll
        for (int r=0;r<2;r++){
          int e=lane+64*r; int a=e>>3, qd=e&7;
          float4 acc=make_float4(0.f,0.f,0.f,0.f);
          #pragma unroll
          for (int k=0;k<8;k++){
            float4 cv=*(const float4*)&sC[(k*16+a)*L6+qd*4];
            FMA4(acc,alr[k],cv);
          }
          *(float4*)&Ck2[pc][a*L6+qd*4]=acc;
        }
      }
    } else if (wid==1){
      if (t>0){
        const size_t bt1=bt-1;
        // Sinv = Linv^T Linv = LinvT-row dot LinvT-row
        #pragma unroll
        for (int q=0;q<4;q++){
          int e=lane+64*q; int a2=e>>4, b2=e&15;
          float s=0.f;
          #pragma unroll
          for (int r=0;r<4;r++)
            s+=dot4(*(const float4*)&LinvT[a2*L0+r*4], *(const float4*)&LinvT[b2*L0+r*4]);
          Sinv[a2*L0+b2]=s;
        }
        // Kg = CP^T @ Sinv * m(t-1)  (reads CPm columns coalesced)
        {
          int i0=lane>>2, aq=lane&3;
          float4 k0=make_float4(0.f,0.f,0.f,0.f), k1=k0;
          #pragma unroll
          for (int bq=0;bq<16;bq++){
            float ca=CPm[bq*L6+i0];
            float cb=CPm[bq*L6+i0+16];
            float4 sv=*(const float4*)&Sinv[bq*L0+aq*4];
            FMA4(k0,ca,sv);
            FMA4(k1,cb,sv);
          }
          float m=mvs2[pp];
          k0.x*=m;k0.y*=m;k0.z*=m;k0.w*=m;
          k1.x*=m;k1.y*=m;k1.z*=m;k1.w*=m;
          *(float4*)&Kg[i0*L0+aq*4]=k0;
          *(float4*)&Kg[(i0+16)*L0+aq*4]=k1;
        }
        // Pf = P - Kg@CP + 1e-3 I -> T3m + store
        {
          const int i0=(lane>>3)*4, j0=(lane&7)*4;
          float4 q0=*(const float4*)&P[(i0+0)*L6+j0];
          float4 q1=*(const float4*)&P[(i0+1)*L6+j0];
          float4 q2=*(const float4*)&P[(i0+2)*L6+j0];
          float4 q3=*(const float4*)&P[(i0+3)*L6+j0];
          #pragma unroll
          for (int q=0;q<4;q++){
            float4 a0=*(const float4*)&Kg[(i0+0)*L0+q*4];
            float4 a1=*(const float4*)&Kg[(i0+1)*L0+q*4];
            float4 a2=*(const float4*)&Kg[(i0+2)*L0+q*4];
            float4 a3=*(const float4*)&Kg[(i0+3)*L0+q*4];
            float4 bv;
            bv=*(const float4*)&CPm[(q*4+0)*L6+j0];
            FMA4(q0,-a0.x,bv); FMA4(q1,-a1.x,bv); FMA4(q2,-a2.x,bv); FMA4(q3,-a3.x,bv);
            bv=*(const float4*)&CPm[(q*4+1)*L6+j0];
            FMA4(q0,-a0.y,bv); FMA4(q1,-a1.y,bv); FMA4(q2,-a2.y,bv); FMA4(q3,-a3.y,bv);
            bv=*(const float4*)&CPm[(q*4+2)*L6+j0];
            FMA4(q0,-a0.z,bv); FMA4(q1,-a1.z,bv); FMA4(q2,-a2.z,bv); FMA4(q3,-a3.z,bv);
            bv=*(const float4*)&CPm[(q*4+3)*L6+j0];
            FMA4(q0,-a0.w,bv); FMA4(q1,-a1.w,bv); FMA4(q2,-a2.w,bv); FMA4(q3,-a3.w,bv);
          }
          int d0=i0-j0;
          if (d0>=0&&d0<4){ if(d0==0)q0.x+=1e-3f; else if(d0==1)q0.y+=1e-3f; else if(d0==2)q0.z+=1e-3f; else q0.w+=1e-3f; }
          int d1=i0+1-j0;
          if (d1>=0&&d1<4){ if(d1==0)q1.x+=1e-3f; else if(d1==1)q1.y+=1e-3f; else if(d1==2)q1.z+=1e-3f; else q1.w+=1e-3f; }
          int d2=i0+2-j0;
          if (d2>=0&&d2<4){ if(d2==0)q2.x+=1e-3f; else if(d2==1)q2.y+=1e-3f; else if(d2==2)q2.z+=1e-3f; else q2.w+=1e-3f; }
          int d3=i0+3-j0;
          if (d3>=0&&d3<4){ if(d3==0)q3.x+=1e-3f; else if(d3==1)q3.y+=1e-3f; else if(d3==2)q3.z+=1e-3f; else q3.w+=1e-3f; }
          *(float4*)&T3m[(i0+0)*L6+j0]=q0;
          *(float4*)&T3m[(i0+1)*L6+j0]=q1;
          *(float4*)&T3m[(i0+2)*L6+j0]=q2;
          *(float4*)&T3m[(i0+3)*L6+j0]=q3;
          *(float4*)&out[off_Pf+bt1*1024+(i0+0)*32+j0]=q0;
          *(float4*)&out[off_Pf+bt1*1024+(i0+1)*32+j0]=q1;
          *(float4*)&out[off_Pf+bt1*1024+(i0+2)*32+j0]=q2;
          *(float4*)&out[off_Pf+bt1*1024+(i0+3)*32+j0]=q3;
        }
        // M3 = Ak(t-1)@T3m -> T1m
        {
          const int i0=(lane>>3)*4, j0=(lane&7)*4;
          float4 q0=make_float4(0.f,0.f,0.f,0.f), q1=q0, q2=q0, q3=q0;
          #pragma unroll 4
          for (int q=0;q<8;q++){
            float4 a0=*(const float4*)&Ak2[pp][(i0+0)*L6+q*4];
            float4 a1=*(const float4*)&Ak2[pp][(i0+1)*L6+q*4];
            float4 a2=*(const float4*)&Ak2[pp][(i0+2)*L6+q*4];
            float4 a3=*(const float4*)&Ak2[pp][(i0+3)*L6+q*4];
            float4 bv;
            bv=*(const float4*)&T3m[(q*4+0)*L6+j0];
            FMA4(q0,a0.x,bv); FMA4(q1,a1.x,bv); FMA4(q2,a2.x,bv); FMA4(q3,a3.x,bv);
            bv=*(const float4*)&T3m[(q*4+1)*L6+j0];
            FMA4(q0,a0.y,bv); FMA4(q1,a1.y,bv); FMA4(q2,a2.y,bv); FMA4(q3,a3.y,bv);
            bv=*(const float4*)&T3m[(q*4+2)*L6+j0];
            FMA4(q0,a0.z,bv); FMA4(q1,a1.z,bv); FMA4(q2,a2.z,bv); FMA4(q3,a3.z,bv);
            bv=*(const float4*)&T3m[(q*4+3)*L6+j0];
            FMA4(q0,a0.w,bv); FMA4(q1,a1.w,bv); FMA4(q2,a2.w,bv); FMA4(q3,a3.w,bv);
          }
          *(float4*)&T1m[(i0+0)*L6+j0]=q0;
          *(float4*)&T1m[(i0+1)*L6+j0]=q1;
          *(float4*)&T1m[(i0+2)*L6+j0]=q2;
          *(float4*)&T1m[(i0+3)*L6+j0]=q3;
        }
        // Pp = T1m@Ak(t-1)^T + Q + 1e-3I -> P(t) + store  (reads Ak rows, dot4 tiles)
        {
          const int i0=(lane>>3)*4, j0=(lane&7)*4;
          float4 q0=*(const float4*)&Qm[(i0+0)*L6+j0];
          float4 q1=*(const float4*)&Qm[(i0+1)*L6+j0];
          float4 q2=*(const float4*)&Qm[(i0+2)*L6+j0];
          float4 q3=*(const float4*)&Qm[(i0+3)*L6+j0];
          int d0=i0-j0;
          if (d0>=0&&d0<4){ if(d0==0)q0.x+=1e-3f; else if(d0==1)q0.y+=1e-3f; else if(d0==2)q0.z+=1e-3f; else q0.w+=1e-3f; }
          int d1=i0+1-j0;
          if (d1>=0&&d1<4){ if(d1==0)q1.x+=1e-3f; else if(d1==1)q1.y+=1e-3f; else if(d1==2)q1.z+=1e-3f; else q1.w+=1e-3f; }
          int d2=i0+2-j0;
          if (d2>=0&&d2<4){ if(d2==0)q2.x+=1e-3f; else if(d2==1)q2.y+=1e-3f; else if(d2==2)q2.z+=1e-3f; else q2.w+=1e-3f; }
          int d3=i0+3-j0;
          if (d3>=0&&d3<4){ if(d3==0)q3.x+=1e-3f; else if(d3==1)q3.y+=1e-3f; else if(d3==2)q3.z+=1e-3f; else q3.w+=1e-3f; }
          #pragma unroll 4
          for (int q=0;q<8;q++){
            float4 t0=*(const float4*)&T1m[(i0+0)*L6+q*4];
            float4 t1=*(const float4*)&T1m[(i0+1)*L6+q*4];
            float4 t2=*(const float4*)&T1m[(i0+2)*L6+q*4];
            float4 t3=*(const float4*)&T1m[(i0+3)*L6+q*4];
            float4 b0=*(const float4*)&Ak2[pp][(j0+0)*L6+q*4];
            float4 b1=*(const float4*)&Ak2[pp][(j0+1)*L6+q*4];
            float4 b2=*(const float4*)&Ak2[pp][(j0+2)*L6+q*4];
            float4 b3=*(const float4*)&Ak2[pp][(j0+3)*L6+q*4];
            q0.x+=dot4(t0,b0); q0.y+=dot4(t0,b1); q0.z+=dot4(t0,b2); q0.w+=dot4(t0,b3);
            q1.x+=dot4(t1,b0); q1.y+=dot4(t1,b1); q1.z+=dot4(t1,b2); q1.w+=dot4(t1,b3);
            q2.x+=dot4(t2,b0); q2.y+=dot4(t2,b1); q2.z+=dot4(t2,b2); q2.w+=dot4(t2,b3);
            q3.x+=dot4(t3,b0); q3.y+=dot4(t3,b1); q3.z+=dot4(t3,b2); q3.w+=dot4(t3,b3);
          }
          *(float4*)&P[(i0+0)*L6+j0]=q0;
          *(float4*)&P[(i0+1)*L6+j0]=q1;
          *(float4*)&P[(i0+2)*L6+j0]=q2;
          *(float4*)&P[(i0+3)*L6+j0]=q3;
          *(float4*)&out[off_Pp+bt1*1024+(i0+0)*32+j0]=q0;
          *(float4*)&out[off_Pp+bt1*1024+(i0+1)*32+j0]=q1;
          *(float4*)&out[off_Pp+bt1*1024+(i0+2)*32+j0]=q2;
          *(float4*)&out[off_Pp+bt1*1024+(i0+3)*32+j0]=q3;
        }
      }
    } else if (wid==2){
      if (t>0){
        const size_t bt1=bt-1;
        float4 zq[8];
        #pragma unroll
        for (int q=0;q<8;q++) zq[q]=*(const float4*)&zc[q*4];
        if (lane<32){
          float s=0.f;
          #pragma unroll
          for (int q=0;q<8;q++) s+=dot4(*(const float4*)&Ak2[pp][lane*L6+q*4], zq[q]);
          float4 bk=*(const float4*)&Bk[lane*4];
          float4 u4=*(const float4*)&uk[0];
          s+=dot4(bk,u4);
          zpred[lane]=s;
          out[off_zp+bt1*32+lane]=s;
        }
        if (lane>=32 && lane<48){
          int a=lane-32;
          float s=0.f;
          #pragma unroll
          for (int q=0;q<8;q++) s+=dot4(*(const float4*)&Ck2[pp][a*L6+q*4], zq[q]);
          out[off_af+bt1*16+a]=s;
        }
        if (lane<16){
          float s=0.f;
          #pragma unroll
          for (int q=0;q<8;q++)
            s+=dot4(*(const float4*)&Ck2[pp][lane*L6+q*4], *(const float4*)&zpred[q*4]);
          out[off_ap+bt1*16+lane]=s;
        }
      }
    } else {
      // wid==3: ak load, zj, aj, ll+alpha_imm
      if (lane<16) ak[lane]=a_seq[bt*16+lane];
      float mv=mask[bt];
      float4 zq[8];
      #pragma unroll
      for (int q=0;q<8;q++) zq[q]=*(const float4*)&zc[q*4];
      #pragma unroll
      for (int r=0;r<4;r++){
        int e=lane+64*r; int k=e>>5, i=e&31;
        float s=0.f;
        #pragma unroll
        for (int q=0;q<8;q++) s+=dot4(*(const float4*)&sA[(k*32+i)*L6+q*4], zq[q]);
        zj[e]=s;
      }
      #pragma unroll
      for (int r=0;r<2;r++){
        int e=lane+64*r; int k=e>>4, a=e&15;
        float s=0.f;
        #pragma unroll
        for (int q=0;q<8;q++) s+=dot4(*(const float4*)&sC[(k*16+a)*L6+q*4], *(const float4*)&zj[k*32+q*4]);
        aj[e]=s;
      }
      if (lane<8){
        float s=0.f;
        #pragma unroll
        for (int q=0;q<4;q++){
          float4 av=*(const float4*)&ak[q*4];
          float4 jv=*(const float4*)&aj[lane*16+q*4];
          float dx=av.x-jv.x, dy=av.y-jv.y, dz=av.z-jv.z, dw=av.w-jv.w;
          s+=dx*dx+dy*dy+dz*dz+dw*dw;
        }
        float llv=-s;
        float m8=llv;
        m8=fmaxf(m8,__shfl_xor(m8,1)); m8=fmaxf(m8,__shfl_xor(m8,2)); m8=fmaxf(m8,__shfl_xor(m8,4));
        float e2=expf(llv-m8);
        float ss=e2;
        ss+=__shfl_xor(ss,1); ss+=__shfl_xor(ss,2); ss+=__shfl_xor(ss,4);
        out[off_ai+bt*8+lane]=e2/ss*mv;
      }
    }
    __syncthreads();

    // ===== Phase B =====
    if (wid==0){
      // znew -> CP -> rk -> S -> chol16 -> solve(LinvT) -> zloc (all in-wave)
      if (lane<32){
        float4 a0v=*(const float4*)&alpha8[0], a1v=*(const float4*)&alpha8[4];
        float s=a0v.x*zj[lane]+a0v.y*zj[32+lane]+a0v.z*zj[64+lane]+a0v.w*zj[96+lane]
               +a1v.x*zj[128+lane]+a1v.y*zj[160+lane]+a1v.z*zj[192+lane]+a1v.w*zj[224+lane];
        znew[lane]=s;
      }
      {
        int qd=lane&7, a0=lane>>3;
        float4 d0=make_float4(0.f,0.f,0.f,0.f), d1=d0;
        #pragma unroll 2
        for (int q=0;q<8;q++){
          float4 c0=*(const float4*)&Ck2[pc][a0*L6+q*4];
          float4 c1=*(const float4*)&Ck2[pc][(a0+8)*L6+q*4];
          float4 p0=*(const float4*)&P[(q*4+0)*L6+qd*4];
          float4 p1=*(const float4*)&P[(q*4+1)*L6+qd*4];
          float4 p2=*(const float4*)&P[(q*4+2)*L6+qd*4];
          float4 p3=*(const float4*)&P[(q*4+3)*L6+qd*4];
          FMA4(d0,c0.x,p0); FMA4(d0,c0.y,p1); FMA4(d0,c0.z,p2); FMA4(d0,c0.w,p3);
          FMA4(d1,c1.x,p0); FMA4(d1,c1.y,p1); FMA4(d1,c1.z,p2); FMA4(d1,c1.w,p3);
        }
        *(float4*)&CPm[a0*L6+qd*4]=d0;
        *(float4*)&CPm[(a0+8)*L6+qd*4]=d1;
      }
      if (lane<16){
        float s=0.f;
        #pragma unroll
        for (int q=0;q<8;q++) s+=dot4(*(const float4*)&Ck2[pc][lane*L6+q*4], *(const float4*)&znew[q*4]);
        rk[lane]=ak[lane]-s;
      }
      {
        int a2=lane>>2, cq=lane&3;
        float s0=0.f,s1=0.f,s2=0.f,s3=0.f;
        #pragma unroll 2
        for (int q=0;q<8;q++){
          float4 cp=*(const float4*)&CPm[a2*L6+q*4];
          s0+=dot4(cp,*(const float4*)&Ck2[pc][(cq*4+0)*L6+q*4]);
          s1+=dot4(cp,*(const float4*)&Ck2[pc][(cq*4+1)*L6+q*4]);
          s2+=dot4(cp,*(const float4*)&Ck2[pc][(cq*4+2)*L6+q*4]);
          s3+=dot4(cp,*(const float4*)&Ck2[pc][(cq*4+3)*L6+q*4]);
        }
        float4 rm=*(const float4*)&Rm[a2*L0+cq*4];
        s0+=rm.x+((a2==cq*4+0)?1e-4f:0.f);
        s1+=rm.y+((a2==cq*4+1)?1e-4f:0.f);
        s2+=rm.z+((a2==cq*4+2)?1e-4f:0.f);
        s3+=rm.w+((a2==cq*4+3)?1e-4f:0.f);
        float4 sv=make_float4(s0,s1,s2,s3);
        *(float4*)&Sm[a2*L0+cq*4]=sv;
        *(float4*)&out[off_S+bt*256+lane*4]=sv;
      }
      {
        int row=lane<16?lane:15;
        float Sr[16], invd[16];
        #pragma unroll
        for (int q=0;q<4;q++){
          float4 v=*(const float4*)&Sm[row*L0+q*4];
          Sr[q*4+0]=v.x; Sr[q*4+1]=v.y; Sr[q*4+2]=v.z; Sr[q*4+3]=v.w;
        }
        #pragma unroll
        for (int c=0;c<16;c++){
          float d=rdlane(Sr[c],c);
          float inv=rsqrtf(d);
          invd[c]=inv;
          float lc=(lane==c)?d*inv:Sr[c]*inv;
          Sr[c]=lc;
          #pragma unroll
          for (int j=c+1;j<16;j++) Sr[j]-=lc*rdlane(lc,j);
        }
        float Li[16], rhs[16];
        #pragma unroll
        for (int r=0;r<16;r++) rhs[r]=(lane==r)?1.f:0.f;
        #pragma unroll
        for (int k=0;k<16;k++){
          float lik=rhs[k]*invd[k];
          Li[k]=lik;
          #pragma unroll
          for (int r=k+1;r<16;r++) rhs[r]-=rdlane(Sr[k],r)*lik;
        }
        // LinvT[col][row] = Linv[row][col] : lane = column, f4 row stores
        if (lane<16){
          #pragma unroll
          for (int q=0;q<4;q++)
            *(float4*)&LinvT[lane*L0+q*4]=make_float4(Li[q*4+0],Li[q*4+1],Li[q*4+2],Li[q*4+3]);
        }
      }
      // ys = Linv @ (m*rk) : ys[r] = sum_k Linv[r][k]*mrk[k] = sum_k LinvT[k][r]*mrk[k]
      if (lane<16){
        float m=mvs2[pc];
        float s=0.f;
        #pragma unroll
        for (int k=0;k<16;k++) s+=LinvT[k*L0+lane]*(m*rk[k]);
        ys[lane]=s;
      }
      // ws = Linv^T @ ys : ws[c] = sum_r Linv[r][c]*ys[r] = dot(LinvT row c, ys)
      if (lane<16){
        float s=0.f;
        #pragma unroll
        for (int q=0;q<4;q++)
          s+=dot4(*(const float4*)&LinvT[lane*L0+q*4], *(const float4*)&ys[q*4]);
        ws[lane]=s;
      }
      // zloc = znew + CP^T@ws  (CPm column reads, coalesced)
      if (lane<32){
        float s=znew[lane];
        #pragma unroll
        for (int a=0;a<16;a++) s+=CPm[a*L6+lane]*ws[a];
        zloc[lane]=s;
        zc[lane]=s;
        out[off_zf+bt*32+lane]=s;
        out[off_zl+bt*32+lane]=s;
      }
    } else if (wid==1){
      // ghl(t+1) = ghs(t) @ Wh ; uk(t) load
      if (lane<48){
        const int c0=lane*4;
        float4 A0=make_float4(0.f,0.f,0.f,0.f), A1=A0, A2=A0, A3=A0;
        #pragma unroll
        for (int q=0;q<16;q++){
          float4 gv=*(const float4*)&ghs[q*4];
          float4 w0=*(const float4*)(Wh+(size_t)(q*4+0)*192+c0);
          float4 w1=*(const float4*)(Wh+(size_t)(q*4+1)*192+c0);
          float4 w2=*(const float4*)(Wh+(size_t)(q*4+2)*192+c0);
          float4 w3=*(const float4*)(Wh+(size_t)(q*4+3)*192+c0);
          FMA4(A0,gv.x,w0); FMA4(A1,gv.y,w1); FMA4(A2,gv.z,w2); FMA4(A3,gv.w,w3);
        }
        float4 g=make_float4(A0.x+A1.x+A2.x+A3.x, A0.y+A1.y+A2.y+A3.y,
                             A0.z+A1.z+A2.z+A3.z, A0.w+A1.w+A2.w+A3.w);
        *(float4*)&ghl[c0]=g;
      }
      if (lane>=48 && lane<52) uk[lane-48]=u_seq[bt*4+(lane-48)];
    } else if (wid==2){
      if (t>0){
        const size_t bt1=bt-1;
        int row=lane<32?lane:31;
        float trl[32];
        #pragma unroll
        for (int q=0;q<8;q++){
          float4 v=*(const float4*)&T3m[row*L6+q*4];
          trl[q*4+0]=v.x; trl[q*4+1]=v.y; trl[q*4+2]=v.z; trl[q*4+3]=v.w;
        }
        #pragma unroll
        for (int c=0;c<32;c++){
          float d=rdlane(trl[c],c);
          float inv=rsqrtf(d);
          float lc=(lane==c)?d*inv:trl[c]*inv;
          trl[c]=lc;
          #pragma unroll
          for (int j=c+1;j<32;j++) trl[j]-=lc*rdlane(lc,j);
        }
        if (lane<32){
          #pragma unroll
          for (int q=0;q<8;q++){
            float t0=(q*4+0<=lane)?trl[q*4+0]:0.f;
            float t1=(q*4+1<=lane)?trl[q*4+1]:0.f;
            float t2=(q*4+2<=lane)?trl[q*4+2]:0.f;
            float t3=(q*4+3<=lane)?trl[q*4+3]:0.f;
            *(float4*)&out[off_tr+bt1*1024+lane*32+q*4]=make_float4(t0,t1,t2,t3);
          }
        }
      }
    } else {
      // wid==3: blends Ak2[pc] + Bk (no transpose stores)
      float alr[8];
      float4 a0v=*(const float4*)&alpha8[0], a1v=*(const float4*)&alpha8[4];
      alr[0]=a0v.x; alr[1]=a0v.y; alr[2]=a0v.z; alr[3]=a0v.w;
      alr[4]=a1v.x; alr[5]=a1v.y; alr[6]=a1v.z; alr[7]=a1v.w;
      #pragma unroll
      for (int r=0;r<4;r++){
        int e=lane+64*r; int i=e>>3, qd=e&7;
        float4 acc=make_float4(0.f,0.f,0.f,0.f);
        #pragma unroll
        for (int k=0;k<8;k++){
          float4 av=*(const float4*)&sA[(k*32+i)*L6+qd*4];
          FMA4(acc,alr[k],av);
        }
        *(float4*)&Ak2[pc][i*L6+qd*4]=acc;
      }
      #pragma unroll
      for (int r=0;r<2;r++){
        int e=lane+64*r;
        float s=0.f;
        #pragma unroll
        for (int k=0;k<8;k++) s+=alr[k]*sBm[k*128+e];
        Bk[e]=s;
      }
    }
    __syncthreads();
  }

  // ===== Epilogue: tail(T-1) =====
  {
    const size_t btL=(size_t)b*T+(T-1);
    const int pl=(T-1)&1;
    if (wid==1){
      #pragma unroll
      for (int q=0;q<4;q++){
        int e=lane+64*q; int a2=e>>4, b2=e&15;
        float s=0.f;
        #pragma unroll
        for (int r=0;r<4;r++)
          s+=dot4(*(const float4*)&LinvT[a2*L0+r*4], *(const float4*)&LinvT[b2*L0+r*4]);
        Sinv[a2*L0+b2]=s;
      }
      {
        int i0=lane>>2, aq=lane&3;
        float4 k0=make_float4(0.f,0.f,0.f,0.f), k1=k0;
        #pragma unroll
        for (int bq=0;bq<16;bq++){
          float ca=CPm[bq*L6+i0];
          float cb=CPm[bq*L6+i0+16];
          float4 sv=*(const float4*)&Sinv[bq*L0+aq*4];
          FMA4(k0,ca,sv);
          FMA4(k1,cb,sv);
        }
        float m=mvs2[pl];
        k0.x*=m;k0.y*=m;k0.z*=m;k0.w*=m;
        k1.x*=m;k1.y*=m;k1.z*=m;k1.w*=m;
        *(float4*)&Kg[i0*L0+aq*4]=k0;
        *(float4*)&Kg[(i0+16)*L0+aq*4]=k1;
      }
      {
        const int i0=(lane>>3)*4, j0=(lane&7)*4;
        float4 q0=*(const float4*)&P[(i0+0)*L6+j0];
        float4 q1=*(const float4*)&P[(i0+1)*L6+j0];
        float4 q2=*(const float4*)&P[(i0+2)*L6+j0];
        float4 q3=*(const float4*)&P[(i0+3)*L6+j0];
        #pragma unroll
        for (int q=0;q<4;q++){
          float4 a0=*(const float4*)&Kg[(i0+0)*L0+q*4];
          float4 a1=*(const float4*)&Kg[(i0+1)*L0+q*4];
          float4 a2=*(const float4*)&Kg[(i0+2)*L0+q*4];
          float4 a3=*(const float4*)&Kg[(i0+3)*L0+q*4];
          float4 bv;
          bv=*(const float4*)&CPm[(q*4+0)*L6+j0];
          FMA4(q0,-a0.x,bv); FMA4(q1,-a1.x,bv); FMA4(q2,-a2.x,bv); FMA4(q3,-a3.x,bv);
          bv=*(const float4*)&CPm[(q*4+1)*L6+j0];
          FMA4(q0,-a0.y,bv); FMA4(q1,-a1.y,bv); FMA4(q2,-a2.y,bv); FMA4(q3,-a3.y,bv);
          bv=*(const float4*)&CPm[(q*4+2)*L6+j0];
          FMA4(q0,-a0.z,bv); FMA4(q1,-a1.z,bv); FMA4(q2,-a2.z,bv); FMA4(q3,-a3.z,bv);
          bv=*(const float4*)&CPm[(q*4+3)*L6+j0];
          FMA4(q0,-a0.w,bv); FMA4(q1,-a1.w,bv); FMA4(q2,-a2.w,bv); FMA4(q3,-a3.w,bv);
        }
        int d0=i0-j0;
        if (d0>=0&&d0<4){ if(d0==0)q0.x+=1e-3f; else if(d0==1)q0.y+=1e-3f; else if(d0==2)q0.z+=1e-3f; else q0.w+=1e-3f; }
        int d1=i0+1-j0;
        if (d1>=0&&d1<4){ if(d1==0)q1.x+=1e-3f; else if(d1==1)q1.y+=1e-3f; else if(d1==2)q1.z+=1e-3f; else q1.w+=1e-3f; }
        int d2=i0+2-j0;
        if (d2>=0&&d2<4){ if(d2==0)q2.x+=1e-3f; else if(d2==1)q2.y+=1e-3f; else if(d2==2)q2.z+=1e-3f; else q2.w+=1e-3f; }
        int d3=i0+3-j0;
        if (d3>=0&&d3<4){ if(d3==0)q3.x+=1e-3f; else if(d3==1)q3.y+=1e-3f; else if(d3==2)q3.z+=1e-3f; else q3.w+=1e-3f; }
        *(float4*)&T3m[(i0+0)*L6+j0]=q0;
        *(float4*)&T3m[(i0+1)*L6+j0]=q1;
        *(float4*)&T3m[(i0+2)*L6+j0]=q2;
        *(float4*)&T3m[(i0+3)*L6+j0]=q3;
        *(float4*)&out[off_Pf+btL*1024+(i0+0)*32+j0]=q0;
        *(float4*)&out[off_Pf+btL*1024+(i0+1)*32+j0]=q1;
        *(float4*)&out[off_Pf+btL*1024+(i0+2)*32+j0]=q2;
        *(float4*)&out[off_Pf+btL*1024+(i0+3)*32+j0]=q3;
      }
      {
        const int i0=(lane>>3)*4, j0=(lane&7)*4;
        float4 q0=make_float4(0.f,0.f,0.f,0.f), q1=q0, q2=q0, q3=q0;
        #pragma unroll 4
        for (int q=0;q<8;q++){
          float4 a0=*(const float4*)&Ak2[pl][(i0+0)*L6+q*4];
          float4 a1=*(const float4*)&Ak2[pl][(i0+1)*L6+q*4];
          float4 a2=*(const float4*)&Ak2[pl][(i0+2)*L6+q*4];
          float4 a3=*(const float4*)&Ak2[pl][(i0+3)*L6+q*4];
          float4 bv;
          bv=*(const float4*)&T3m[(q*4+0)*L6+j0];
          FMA4(q0,a0.x,bv); FMA4(q1,a1.x,bv); FMA4(q2,a2.x,bv); FMA4(q3,a3.x,bv);
          bv=*(const float4*)&T3m[(q*4+1)*L6+j0];
          FMA4(q0,a0.y,bv); FMA4(q1,a1.y,bv); FMA4(q2,a2.y,bv); FMA4(q3,a3.y,bv);
          bv=*(const float4*)&T3m[(q*4+2)*L6+j0];
          FMA4(q0,a0.z,bv); FMA4(q1,a1.z,bv); FMA4(q2,a2.z,bv); FMA4(q3,a3.z,bv);
          bv=*(const float4*)&T3m[(q*4+3)*L6+j0];
          FMA4(q0,a0.w,bv); FMA4(q1,a1.w,bv); FMA4(q2,a2.w,bv); FMA4(q3,a3.w,bv);
        }
        *(float4*)&T1m[(i0+0)*L6+j0]=q0;
        *(float4*)&T1m[(i0+1)*L6+j0]=q1;
        *(float4*)&T1m[(i0+2)*L6+j0]=q2;
        *(float4*)&T1m[(i0+3)*L6+j0]=q3;
      }
      {
        const int i0=(lane>>3)*4, j0=(lane&7)*4;
        float4 q0=*(const float4*)&Qm[(i0+0)*L6+j0];
        float4 q1=*(const float4*)&Qm[(i0+1)*L6+j0];
        float4 q2=*(const float4*)&Qm[(i0+2)*L6+j0];
        float4 q3=*(const float4*)&Qm[(i0+3)*L6+j0];
        int d0=i0-j0;
        if (d0>=0&&d0<4){ if(d0==0)q0.x+=1e-3f; else if(d0==1)q0.y+=1e-3f; else if(d0==2)q0.z+=1e-3f; else q0.w+=1e-3f; }
        int d1=i0+1-j0;
        if (d1>=0&&d1<4){ if(d1==0)q1.x+=1e-3f; else if(d1==1)q1.y+=1e-3f; else if(d1==2)q1.z+=1e-3f; else q1.w+=1e-3f; }
        int d2=i0+2-j0;
        if (d2>=0&&d2<4){ if(d2==0)q2.x+=1e-3f; else if(d2==1)q2.y+=1e-3f; else if(d2==2)q2.z+=1e-3f; else q2.w+=1e-3f; }
        int d3=i0+3-j0;
        if (d3>=0&&d3<4){ if(d3==0)q3.x+=1e-3f; else if(d3==1)q3.y+=1e-3f; else if(d3==2)q3.z+=1e-3f; else q3.w+=1e-3f; }
        #pragma unroll 4
        for (int q=0;q<8;q++){
          float4 t0=*(const float4*)&T1m[(i0+0)*L6+q*4];
          float4 t1=*(const float4*)&T1m[(i0+1)*L6+q*4];
          float4 t2=*(const float4*)&T1m[(i0+2)*L6+q*4];
          float4 t3=*(const float4*)&T1m[(i0+3)*L6+q*4];
          float4 b0=*(const float4*)&Ak2[pl][(j0+0)*L6+q*4];
          float4 b1=*(const float4*)&Ak2[pl][(j0+1)*L6+q*4];
          float4 b2=*(const float4*)&Ak2[pl][(j0+2)*L6+q*4];
          float4 b3=*(const float4*)&Ak2[pl][(j0+3)*L6+q*4];
          q0.x+=dot4(t0,b0); q0.y+=dot4(t0,b1); q0.z+=dot4(t0,b2); q0.w+=dot4(t0,b3);
          q1.x+=dot4(t1,b0); q1.y+=dot4(t1,b1); q1.z+=dot4(t1,b2); q1.w+=dot4(t1,b3);
          q2.x+=dot4(t2,b0); q2.y+=dot4(t2,b1); q2.z+=dot4(t2,b2); q2.w+=dot4(t2,b3);
          q3.x+=dot4(t3,b0); q3.y+=dot4(t3,b1); q3.z+=dot4(t3,b2); q3.w+=dot4(t3,b3);
        }
        *(float4*)&out[off_Pp+btL*1024+(i0+0)*32+j0]=q0;
        *(float4*)&out[off_Pp+btL*1024+(i0+1)*32+j0]=q1;
        *(float4*)&out[off_Pp+btL*1024+(i0+2)*32+j0]=q2;
        *(float4*)&out[off_Pp+btL*1024+(i0+3)*32+j0]=q3;
      }
    } else if (wid==2){
      float4 zq[8];
      #pragma unroll
      for (int q=0;q<8;q++) zq[q]=*(const float4*)&zc[q*4];
      if (lane<32){
        float s=0.f;
        #pragma unroll
        for (int q=0;q<8;q++) s+=dot4(*(const float4*)&Ak2[pl][lane*L6+q*4], zq[q]);
        float4 bk=*(const float4*)&Bk[lane*4];
        float4 u4=*(const float4*)&uk[0];
        s+=dot4(bk,u4);
        zpred[lane]=s;
        out[off_zp+btL*32+lane]=s;
      }
      if (lane>=32 && lane<48){
        int a=lane-32;
        float s=0.f;
        #pragma unroll
        for (int q=0;q<8;q++) s+=dot4(*(const float4*)&Ck2[pl][a*L6+q*4], zq[q]);
        out[off_af+btL*16+a]=s;
      }
      if (lane<16){
        float s=0.f;
        #pragma unroll
        for (int q=0;q<8;q++)
          s+=dot4(*(const float4*)&Ck2[pl][lane*L6+q*4], *(const float4*)&zpred[q*4]);
        out[off_ap+btL*16+lane]=s;
      }
    }
    __syncthreads();
    if (wid==2){
      int row=lane<32?lane:31;
      float trl[32];
      #pragma unroll
      for (int q=0;q<8;q++){
        float4 v=*(const float4*)&T3m[row*L6+q*4];
        trl[q*4+0]=v.x; trl[q*4+1]=v.y; trl[q*4+2]=v.z; trl[q*4+3]=v.w;
      }
      #pragma unroll
      for (int c=0;c<32;c++){
        float d=rdlane(trl[c],c);
        float inv=rsqrtf(d);
        float lc=(lane==c)?d*inv:trl[c]*inv;
        trl[c]=lc;
        #pragma unroll
        for (int j=c+1;j<32;j++) trl[j]-=lc*rdlane(lc,j);
      }
      if (lane<32){
        #pragma unroll
        for (int q=0;q<8;q++){
          float t0=(q*4+0<=lane)?trl[q*4+0]:0.f;
          float t1=(q*4+1<=lane)?trl[q*4+1]:0.f;
          float t2=(q*4+2<=lane)?trl[q*4+2]:0.f;
          float t3=(q*4+3<=lane)?trl[q*4+3]:0.f;
          *(float4*)&out[off_tr+btL*1024+lane*32+q*4]=make_float4(t0,t1,t2,t3);
        }
      }
    }
  }
}

extern "C" void kernel_launch(void* const* d_in, const int* in_sizes, int n_in,
                              void* d_out, int out_size, void* d_ws, size_t ws_size,
                              hipStream_t stream) {
  kf_fwd<<<128, NT, 0, stream>>>(
    (const float*)d_in[0],  // a_seq
    (const float*)d_in[1],  // h_obs
    (const float*)d_in[2],  // A_matrices
    (const float*)d_in[3],  // C_matrices
    (const float*)d_in[4],  // B_matrices
    (const float*)d_in[5],  // u_seq
    (const float*)d_in[6],  // mask
    (const float*)d_in[7],  // P_0
    (const float*)d_in[8],  // mat_Q
    (const float*)d_in[9],  // mat_R
    (const float*)d_in[10], // gru_Wx
    (const float*)d_in[11], // gru_Wh
    (const float*)d_in[12], // gru_b
    (const float*)d_in[13], // out_W
    (const float*)d_in[14], // out_b
    (float*)d_out);
}

// Round 14
// 2414.270 us; speedup vs baseline: 1.0321x; 1.0321x over previous
//
#include <hip/hip_runtime.h>
#include <math.h>

#define NT 256
#define FMA4(acc,u,bv) {acc.x+=(u)*(bv).x; acc.y+=(u)*(bv).y; acc.z+=(u)*(bv).z; acc.w+=(u)*(bv).w;}

__device__ __forceinline__ float sigf(float x){ return 1.0f/(1.0f+expf(-x)); }
__device__ __forceinline__ float rdlane(float v, int l){
  return __int_as_float(__builtin_amdgcn_readlane(__float_as_int(v), l));
}
__device__ __forceinline__ float dot4(float4 a, float4 b){
  return a.x*b.x + a.y*b.y + a.z*b.z + a.w*b.w;
}

__launch_bounds__(NT, 1)
__global__ void kf_fwd(const float* __restrict__ a_seq, const float* __restrict__ h_obs,
  const float* __restrict__ Amat, const float* __restrict__ Cmat, const float* __restrict__ Bmat,
  const float* __restrict__ u_seq, const float* __restrict__ mask, const float* __restrict__ P0,
  const float* __restrict__ matQ, const float* __restrict__ matR,
  const float* __restrict__ Wx, const float* __restrict__ Wh, const float* __restrict__ gbias,
  const float* __restrict__ outW, const float* __restrict__ outb, float* __restrict__ out)
{
  constexpr int T=256, B=128;
  constexpr int L6=36, L0=20;
  constexpr size_t BT=(size_t)B*T;
  const size_t off_zf=0;
  const size_t off_Pf=off_zf+BT*32;
  const size_t off_zl=off_Pf+BT*1024;
  const size_t off_tr=off_zl+BT*32;
  const size_t off_zp=off_tr+BT*1024;
  const size_t off_Pp=off_zp+BT*32;
  const size_t off_af=off_Pp+BT*1024;
  const size_t off_ap=off_af+BT*16;
  const size_t off_S =off_ap+BT*16;
  const size_t off_al=off_S +BT*256;
  const size_t off_ai=off_al+BT*8;
  const size_t off_R =off_ai+BT*8;
  const size_t off_Q =off_R +256;

  __shared__ __align__(16) float sA[8*32*L6];
  __shared__ __align__(16) float sC[8*16*L6];
  __shared__ __align__(16) float W12[48*192];
  __shared__ __align__(16) float gxh[192];
  __shared__ __align__(16) float sBm[1024];
  __shared__ __align__(16) float souWT[512];
  __shared__ __align__(16) float soutb8[8];
  __shared__ __align__(16) float P[32*L6], T1m[32*L6], T3m[32*L6], Qm[32*L6];
  __shared__ __align__(16) float Ak2[2][32*L6], AkT2[2][32*L6];
  __shared__ __align__(16) float Ck2[2][16*L6];
  __shared__ __align__(16) float CPm[16*L6];
  __shared__ __align__(16) float CPT[32*L0], Kg[32*L0];
  __shared__ __align__(16) float Sm[16*L0], Rm[16*L0], Sinv[16*L0];
  __shared__ __align__(16) float Linv[16*17];
  __shared__ __align__(16) float Bk[128];
  __shared__ __align__(16) float zj[256], aj[128];
  __shared__ __align__(16) float gx[192], ghl[192];
  __shared__ __align__(16) float zc[32], znew[32], zloc[32], zpred[32], ghs[64];
  __shared__ __align__(16) float aprevv[16], hob[16];
  __shared__ __align__(16) float ak[16], uk[4], rk[16], alpha8[8];
  __shared__ __align__(16) float ys[16], ws[16];
  __shared__ float mvs2[2];

  const int tid  = threadIdx.x;
  const int wid  = tid>>6;
  const int lane = tid&63;
  const int b = blockIdx.x;

  // ---------- init ----------
  for (int e=tid; e<8192; e+=NT){ int k=e>>10, i=(e>>5)&31, j=e&31; sA[(k*32+i)*L6+j]=Amat[e]; }
  for (int e=tid; e<4096; e+=NT){ int k=e>>9, a=(e>>5)&15, i=e&31; sC[(k*16+a)*L6+i]=Cmat[e]; }
  for (int e=tid; e<1024; e+=NT) sBm[e]=Bmat[e];
  for (int e=tid; e<512; e+=NT){ int r=e>>6, q=e&63; souWT[r*64+q]=outW[q*8+r]; }
  if (tid<8) soutb8[tid]=outb[tid];
  for (int e=tid; e<1024; e+=NT){
    int i=e>>5, j=e&31;
    float s=0.f;
    #pragma unroll 8
    for (int k=0;k<32;k++) s += matQ[i*32+k]*matQ[j*32+k];
    Qm[i*L6+j]=s+(i==j?0.001f:0.f);
    P[i*L6+j]=P0[e];
  }
  for (int e=tid; e<256; e+=NT){
    int i=e>>4, j=e&15;
    float s=0.f;
    #pragma unroll
    for (int k=0;k<16;k++) s += matR[i*16+k]*matR[j*16+k];
    Rm[i*L0+j]=s+(i==j?0.001f:0.f);
  }
  for (int e=tid; e<16*L6; e+=NT){ Ck2[0][e]=0.f; Ck2[1][e]=0.f; }
  if (tid<32) zc[tid]=0.f;
  if (tid<64) ghs[tid]=0.f;
  for (int e=tid; e<192; e+=NT) ghl[e]=0.f;
  if (tid<16) hob[tid]=h_obs[b*16+tid];
  __syncthreads();

  // W1 rows + gxh
  if (tid<48){
    const int c0=tid*4;
    #pragma unroll
    for (int a=0;a<16;a++)
      *(float4*)&W12[(32+a)*192+c0] = *(const float4*)(Wx+(size_t)a*192+c0);
    float4 acc=*(const float4*)(gbias+c0);
    #pragma unroll
    for (int i=0;i<16;i++){
      float4 w=*(const float4*)(Wx+(size_t)(16+i)*192+c0);
      float hv=hob[i];
      FMA4(acc,hv,w);
    }
    *(float4*)&gxh[c0]=acc;
  }
  // W2 = Wx[32:64] + M,  M = sum_k CA_k^T @ Wx[64+16k : 80+16k]
  for (int ic=0; ic<4; ++ic){
    float4 Mi[8];
    if (tid<48){
      const int c0=tid*4;
      #pragma unroll
      for (int ii=0;ii<8;ii++)
        Mi[ii]=*(const float4*)(Wx+(size_t)(32+ic*8+ii)*192+c0);
    }
    for (int k=0;k<8;k++){
      __syncthreads();
      if (tid<128){
        int e=tid; int a=e>>3, ii=e&7; int i=ic*8+ii;
        float s=0.f;
        #pragma unroll 8
        for (int j=0;j<32;j++) s+=sC[(k*16+a)*L6+j]*sA[(k*32+j)*L6+i];
        Kg[a*8+ii]=s;
      }
      __syncthreads();
      if (tid<48){
        const int c0=tid*4;
        #pragma unroll
        for (int a=0;a<16;a++){
          float4 w=*(const float4*)(Wx+(size_t)(64+16*k+a)*192+c0);
          #pragma unroll
          for (int ii=0;ii<8;ii++){
            float ca=Kg[a*8+ii];
            FMA4(Mi[ii],ca,w);
          }
        }
      }
    }
    if (tid<48){
      const int c0=tid*4;
      #pragma unroll
      for (int ii=0;ii<8;ii++)
        *(float4*)&W12[(ic*8+ii)*192+c0]=Mi[ii];
    }
  }
  if (b==0){
    for (int e=tid;e<256;e+=NT) out[off_R+e]=Rm[(e>>4)*L0+(e&15)];
    for (int e=tid;e<1024;e+=NT) out[off_Q+e]=Qm[(e>>5)*L6+(e&31)];
  }
  __syncthreads();

  for (int t=0;t<T;t++){
    const size_t bt=(size_t)b*T+t;
    const int pc=t&1, pp=pc^1;

    // ===== Phase A =====
    if (wid==0){
      // head(t): aprev -> gx -> gates -> logits -> alpha -> Ck(t) blend (in-wave)
      if (lane==0) mvs2[pc]=mask[bt];
      float4 zq[8];
      #pragma unroll
      for (int q=0;q<8;q++) zq[q]=*(const float4*)&zc[q*4];
      if (lane<16){
        float s=0.f;
        #pragma unroll
        for (int q=0;q<8;q++) s+=dot4(*(const float4*)&Ck2[pp][lane*L6+q*4], zq[q]);
        aprevv[lane]=s;
      }
      if (lane<48){
        const int c0=lane*4;
        float4 A0=*(const float4*)&gxh[c0];
        float4 A1=make_float4(0.f,0.f,0.f,0.f), A2=A1, A3=A1;
        #pragma unroll
        for (int q=0;q<8;q++){
          float4 zv=zq[q];
          float4 w0=*(const float4*)&W12[(q*4+0)*192+c0];
          float4 w1=*(const float4*)&W12[(q*4+1)*192+c0];
          float4 w2=*(const float4*)&W12[(q*4+2)*192+c0];
          float4 w3=*(const float4*)&W12[(q*4+3)*192+c0];
          FMA4(A0,zv.x,w0); FMA4(A1,zv.y,w1); FMA4(A2,zv.z,w2); FMA4(A3,zv.w,w3);
        }
        #pragma unroll
        for (int q=0;q<4;q++){
          float4 av=*(const float4*)&aprevv[q*4];
          float4 w0=*(const float4*)&W12[(32+q*4+0)*192+c0];
          float4 w1=*(const float4*)&W12[(32+q*4+1)*192+c0];
          float4 w2=*(const float4*)&W12[(32+q*4+2)*192+c0];
          float4 w3=*(const float4*)&W12[(32+q*4+3)*192+c0];
          FMA4(A0,av.x,w0); FMA4(A1,av.y,w1); FMA4(A2,av.z,w2); FMA4(A3,av.w,w3);
        }
        float4 g=make_float4(A0.x+A1.x+A2.x+A3.x, A0.y+A1.y+A2.y+A3.y,
                             A0.z+A1.z+A2.z+A3.z, A0.w+A1.w+A2.w+A3.w);
        *(float4*)&gx[c0]=g;
      }
      {
        float r =sigf(gx[lane]+ghl[lane]);
        float zg=sigf(gx[64+lane]+ghl[64+lane]);
        float n =tanhf(gx[128+lane]+r*ghl[128+lane]);
        float h=ghs[lane];
        ghs[lane]=(1.f-zg)*n+zg*h;
      }
      if (lane<8){
        float s=soutb8[lane];
        #pragma unroll
        for (int q=0;q<16;q++){
          float4 g=*(const float4*)&ghs[q*4];
          float4 w=*(const float4*)&souWT[lane*64+q*4];
          s+=dot4(g,w);
        }
        float m8=s;
        m8=fmaxf(m8,__shfl_xor(m8,1)); m8=fmaxf(m8,__shfl_xor(m8,2)); m8=fmaxf(m8,__shfl_xor(m8,4));
        float e2=expf(s-m8);
        float ss=e2;
        ss+=__shfl_xor(ss,1); ss+=__shfl_xor(ss,2); ss+=__shfl_xor(ss,4);
        float av=e2/ss;
        alpha8[lane]=av;
        out[off_al+bt*8+lane]=av;
      }
      // Ck(t) blend (reads alpha8 written in-wave above)
      {
        float alr[8];
        float4 a0v=*(const float4*)&alpha8[0], a1v=*(const float4*)&alpha8[4];
        alr[0]=a0v.x; alr[1]=a0v.y; alr[2]=a0v.z; alr[3]=a0v.w;
        alr[4]=a1v.x; alr[5]=a1v.y; alr[6]=a1v.z; alr[7]=a1v.w;
        #pragma unroll
        for (int r=0;r<2;r++){
          int e=lane+64*r; int a=e>>3, qd=e&7;
          float4 acc=make_float4(0.f,0.f,0.f,0.f);
          #pragma unroll
          for (int k=0;k<8;k++){
            float4 cv=*(const float4*)&sC[(k*16+a)*L6+qd*4];
            FMA4(acc,alr[k],cv);
          }
          *(float4*)&Ck2[pc][a*L6+qd*4]=acc;
        }
      }
    } else if (wid==1){
      if (t>0){
        const size_t bt1=bt-1;
        // Sinv = Linv^T Linv
        #pragma unroll
        for (int q=0;q<4;q++){
          int e=lane+64*q; int a2=e>>4, b2=e&15;
          float s=0.f;
          #pragma unroll
          for (int k=0;k<16;k++) s+=Linv[k*17+a2]*Linv[k*17+b2];
          Sinv[a2*L0+b2]=s;
        }
        // Kg = CPT@Sinv * m(t-1)
        {
          int i0=lane>>2, aq=lane&3;
          float4 k0=make_float4(0.f,0.f,0.f,0.f), k1=k0;
          #pragma unroll
          for (int q=0;q<4;q++){
            float4 ca=*(const float4*)&CPT[i0*L0+q*4];
            float4 cb=*(const float4*)&CPT[(i0+16)*L0+q*4];
            float4 v0=*(const float4*)&Sinv[(q*4+0)*L0+aq*4];
            float4 v1=*(const float4*)&Sinv[(q*4+1)*L0+aq*4];
            float4 v2=*(const float4*)&Sinv[(q*4+2)*L0+aq*4];
            float4 v3=*(const float4*)&Sinv[(q*4+3)*L0+aq*4];
            FMA4(k0,ca.x,v0); FMA4(k0,ca.y,v1); FMA4(k0,ca.z,v2); FMA4(k0,ca.w,v3);
            FMA4(k1,cb.x,v0); FMA4(k1,cb.y,v1); FMA4(k1,cb.z,v2); FMA4(k1,cb.w,v3);
          }
          float m=mvs2[pp];
          k0.x*=m;k0.y*=m;k0.z*=m;k0.w*=m;
          k1.x*=m;k1.y*=m;k1.z*=m;k1.w*=m;
          *(float4*)&Kg[i0*L0+aq*4]=k0;
          *(float4*)&Kg[(i0+16)*L0+aq*4]=k1;
        }
        // Pf = P - Kg@CP + 1e-3 I -> T3m + store
        {
          const int i0=(lane>>3)*4, j0=(lane&7)*4;
          float4 q0=*(const float4*)&P[(i0+0)*L6+j0];
          float4 q1=*(const float4*)&P[(i0+1)*L6+j0];
          float4 q2=*(const float4*)&P[(i0+2)*L6+j0];
          float4 q3=*(const float4*)&P[(i0+3)*L6+j0];
          #pragma unroll
          for (int q=0;q<4;q++){
            float4 a0=*(const float4*)&Kg[(i0+0)*L0+q*4];
            float4 a1=*(const float4*)&Kg[(i0+1)*L0+q*4];
            float4 a2=*(const float4*)&Kg[(i0+2)*L0+q*4];
            float4 a3=*(const float4*)&Kg[(i0+3)*L0+q*4];
            float4 bv;
            bv=*(const float4*)&CPm[(q*4+0)*L6+j0];
            FMA4(q0,-a0.x,bv); FMA4(q1,-a1.x,bv); FMA4(q2,-a2.x,bv); FMA4(q3,-a3.x,bv);
            bv=*(const float4*)&CPm[(q*4+1)*L6+j0];
            FMA4(q0,-a0.y,bv); FMA4(q1,-a1.y,bv); FMA4(q2,-a2.y,bv); FMA4(q3,-a3.y,bv);
            bv=*(const float4*)&CPm[(q*4+2)*L6+j0];
            FMA4(q0,-a0.z,bv); FMA4(q1,-a1.z,bv); FMA4(q2,-a2.z,bv); FMA4(q3,-a3.z,bv);
            bv=*(const float4*)&CPm[(q*4+3)*L6+j0];
            FMA4(q0,-a0.w,bv); FMA4(q1,-a1.w,bv); FMA4(q2,-a2.w,bv); FMA4(q3,-a3.w,bv);
          }
          int d0=i0-j0;
          if (d0>=0&&d0<4){ if(d0==0)q0.x+=1e-3f; else if(d0==1)q0.y+=1e-3f; else if(d0==2)q0.z+=1e-3f; else q0.w+=1e-3f; }
          int d1=i0+1-j0;
          if (d1>=0&&d1<4){ if(d1==0)q1.x+=1e-3f; else if(d1==1)q1.y+=1e-3f; else if(d1==2)q1.z+=1e-3f; else q1.w+=1e-3f; }
          int d2=i0+2-j0;
          if (d2>=0&&d2<4){ if(d2==0)q2.x+=1e-3f; else if(d2==1)q2.y+=1e-3f; else if(d2==2)q2.z+=1e-3f; else q2.w+=1e-3f; }
          int d3=i0+3-j0;
          if (d3>=0&&d3<4){ if(d3==0)q3.x+=1e-3f; else if(d3==1)q3.y+=1e-3f; else if(d3==2)q3.z+=1e-3f; else q3.w+=1e-3f; }
          *(float4*)&T3m[(i0+0)*L6+j0]=q0;
          *(float4*)&T3m[(i0+1)*L6+j0]=q1;
          *(float4*)&T3m[(i0+2)*L6+j0]=q2;
          *(float4*)&T3m[(i0+3)*L6+j0]=q3;
          *(float4*)&out[off_Pf+bt1*1024+(i0+0)*32+j0]=q0;
          *(float4*)&out[off_Pf+bt1*1024+(i0+1)*32+j0]=q1;
          *(float4*)&out[off_Pf+bt1*1024+(i0+2)*32+j0]=q2;
          *(float4*)&out[off_Pf+bt1*1024+(i0+3)*32+j0]=q3;
        }
        // M3 = Ak(t-1)@T3m -> T1m  (in-wave: T3m written above by this wave)
        {
          const int i0=(lane>>3)*4, j0=(lane&7)*4;
          float4 q0=make_float4(0.f,0.f,0.f,0.f), q1=q0, q2=q0, q3=q0;
          #pragma unroll 4
          for (int q=0;q<8;q++){
            float4 a0=*(const float4*)&Ak2[pp][(i0+0)*L6+q*4];
            float4 a1=*(const float4*)&Ak2[pp][(i0+1)*L6+q*4];
            float4 a2=*(const float4*)&Ak2[pp][(i0+2)*L6+q*4];
            float4 a3=*(const float4*)&Ak2[pp][(i0+3)*L6+q*4];
            float4 bv;
            bv=*(const float4*)&T3m[(q*4+0)*L6+j0];
            FMA4(q0,a0.x,bv); FMA4(q1,a1.x,bv); FMA4(q2,a2.x,bv); FMA4(q3,a3.x,bv);
            bv=*(const float4*)&T3m[(q*4+1)*L6+j0];
            FMA4(q0,a0.y,bv); FMA4(q1,a1.y,bv); FMA4(q2,a2.y,bv); FMA4(q3,a3.y,bv);
            bv=*(const float4*)&T3m[(q*4+2)*L6+j0];
            FMA4(q0,a0.z,bv); FMA4(q1,a1.z,bv); FMA4(q2,a2.z,bv); FMA4(q3,a3.z,bv);
            bv=*(const float4*)&T3m[(q*4+3)*L6+j0];
            FMA4(q0,a0.w,bv); FMA4(q1,a1.w,bv); FMA4(q2,a2.w,bv); FMA4(q3,a3.w,bv);
          }
          *(float4*)&T1m[(i0+0)*L6+j0]=q0;
          *(float4*)&T1m[(i0+1)*L6+j0]=q1;
          *(float4*)&T1m[(i0+2)*L6+j0]=q2;
          *(float4*)&T1m[(i0+3)*L6+j0]=q3;
        }
        // Pp = T1m@AkT(t-1) + Q + 1e-3I -> P(t) + store
        {
          const int i0=(lane>>3)*4, j0=(lane&7)*4;
          float4 q0=*(const float4*)&Qm[(i0+0)*L6+j0];
          float4 q1=*(const float4*)&Qm[(i0+1)*L6+j0];
          float4 q2=*(const float4*)&Qm[(i0+2)*L6+j0];
          float4 q3=*(const float4*)&Qm[(i0+3)*L6+j0];
          int d0=i0-j0;
          if (d0>=0&&d0<4){ if(d0==0)q0.x+=1e-3f; else if(d0==1)q0.y+=1e-3f; else if(d0==2)q0.z+=1e-3f; else q0.w+=1e-3f; }
          int d1=i0+1-j0;
          if (d1>=0&&d1<4){ if(d1==0)q1.x+=1e-3f; else if(d1==1)q1.y+=1e-3f; else if(d1==2)q1.z+=1e-3f; else q1.w+=1e-3f; }
          int d2=i0+2-j0;
          if (d2>=0&&d2<4){ if(d2==0)q2.x+=1e-3f; else if(d2==1)q2.y+=1e-3f; else if(d2==2)q2.z+=1e-3f; else q2.w+=1e-3f; }
          int d3=i0+3-j0;
          if (d3>=0&&d3<4){ if(d3==0)q3.x+=1e-3f; else if(d3==1)q3.y+=1e-3f; else if(d3==2)q3.z+=1e-3f; else q3.w+=1e-3f; }
          #pragma unroll 4
          for (int q=0;q<8;q++){
            float4 a0=*(const float4*)&T1m[(i0+0)*L6+q*4];
            float4 a1=*(const float4*)&T1m[(i0+1)*L6+q*4];
            float4 a2=*(const float4*)&T1m[(i0+2)*L6+q*4];
            float4 a3=*(const float4*)&T1m[(i0+3)*L6+q*4];
            float4 bv;
            bv=*(const float4*)&AkT2[pp][(q*4+0)*L6+j0];
            FMA4(q0,a0.x,bv); FMA4(q1,a1.x,bv); FMA4(q2,a2.x,bv); FMA4(q3,a3.x,bv);
            bv=*(const float4*)&AkT2[pp][(q*4+1)*L6+j0];
            FMA4(q0,a0.y,bv); FMA4(q1,a1.y,bv); FMA4(q2,a2.y,bv); FMA4(q3,a3.y,bv);
            bv=*(const float4*)&AkT2[pp][(q*4+2)*L6+j0];
            FMA4(q0,a0.z,bv); FMA4(q1,a1.z,bv); FMA4(q2,a2.z,bv); FMA4(q3,a3.z,bv);
            bv=*(const float4*)&AkT2[pp][(q*4+3)*L6+j0];
            FMA4(q0,a0.w,bv); FMA4(q1,a1.w,bv); FMA4(q2,a2.w,bv); FMA4(q3,a3.w,bv);
          }
          *(float4*)&P[(i0+0)*L6+j0]=q0;
          *(float4*)&P[(i0+1)*L6+j0]=q1;
          *(float4*)&P[(i0+2)*L6+j0]=q2;
          *(float4*)&P[(i0+3)*L6+j0]=q3;
          *(float4*)&out[off_Pp+bt1*1024+(i0+0)*32+j0]=q0;
          *(float4*)&out[off_Pp+bt1*1024+(i0+1)*32+j0]=q1;
          *(float4*)&out[off_Pp+bt1*1024+(i0+2)*32+j0]=q2;
          *(float4*)&out[off_Pp+bt1*1024+(i0+3)*32+j0]=q3;
        }
      }
    } else if (wid==2){
      if (t>0){
        const size_t bt1=bt-1;
        float4 zq[8];
        #pragma unroll
        for (int q=0;q<8;q++) zq[q]=*(const float4*)&zc[q*4];
        if (lane<32){
          float s=0.f;
          #pragma unroll
          for (int q=0;q<8;q++) s+=dot4(*(const float4*)&Ak2[pp][lane*L6+q*4], zq[q]);
          float4 bk=*(const float4*)&Bk[lane*4];
          float4 u4=*(const float4*)&uk[0];
          s+=dot4(bk,u4);
          zpred[lane]=s;
          out[off_zp+bt1*32+lane]=s;
        }
        if (lane>=32 && lane<48){
          int a=lane-32;
          float s=0.f;
          #pragma unroll
          for (int q=0;q<8;q++) s+=dot4(*(const float4*)&Ck2[pp][a*L6+q*4], zq[q]);
          out[off_af+bt1*16+a]=s;
        }
        if (lane<16){
          float s=0.f;
          #pragma unroll
          for (int q=0;q<8;q++)
            s+=dot4(*(const float4*)&Ck2[pp][lane*L6+q*4], *(const float4*)&zpred[q*4]);
          out[off_ap+bt1*16+lane]=s;
        }
      }
    } else {
      // wid==3: ak load, zj, aj, ll+alpha_imm
      if (lane<16) ak[lane]=a_seq[bt*16+lane];
      float mv=mask[bt];
      float4 zq[8];
      #pragma unroll
      for (int q=0;q<8;q++) zq[q]=*(const float4*)&zc[q*4];
      #pragma unroll
      for (int r=0;r<4;r++){
        int e=lane+64*r; int k=e>>5, i=e&31;
        float s=0.f;
        #pragma unroll
        for (int q=0;q<8;q++) s+=dot4(*(const float4*)&sA[(k*32+i)*L6+q*4], zq[q]);
        zj[e]=s;
      }
      #pragma unroll
      for (int r=0;r<2;r++){
        int e=lane+64*r; int k=e>>4, a=e&15;
        float s=0.f;
        #pragma unroll
        for (int q=0;q<8;q++) s+=dot4(*(const float4*)&sC[(k*16+a)*L6+q*4], *(const float4*)&zj[k*32+q*4]);
        aj[e]=s;
      }
      if (lane<8){
        float s=0.f;
        #pragma unroll
        for (int q=0;q<4;q++){
          float4 av=*(const float4*)&ak[q*4];
          float4 jv=*(const float4*)&aj[lane*16+q*4];
          float dx=av.x-jv.x, dy=av.y-jv.y, dz=av.z-jv.z, dw=av.w-jv.w;
          s+=dx*dx+dy*dy+dz*dz+dw*dw;
        }
        float llv=-s;
        float m8=llv;
        m8=fmaxf(m8,__shfl_xor(m8,1)); m8=fmaxf(m8,__shfl_xor(m8,2)); m8=fmaxf(m8,__shfl_xor(m8,4));
        float e2=expf(llv-m8);
        float ss=e2;
        ss+=__shfl_xor(ss,1); ss+=__shfl_xor(ss,2); ss+=__shfl_xor(ss,4);
        out[off_ai+bt*8+lane]=e2/ss*mv;
      }
    }
    __syncthreads();

    // ===== Phase B =====
    if (wid==0){
      // znew -> CP -> rk -> S -> chol16 -> solve -> zloc (all in-wave)
      if (lane<32){
        float4 a0v=*(const float4*)&alpha8[0], a1v=*(const float4*)&alpha8[4];
        float s=a0v.x*zj[lane]+a0v.y*zj[32+lane]+a0v.z*zj[64+lane]+a0v.w*zj[96+lane]
               +a1v.x*zj[128+lane]+a1v.y*zj[160+lane]+a1v.z*zj[192+lane]+a1v.w*zj[224+lane];
        znew[lane]=s;
      }
      {
        int qd=lane&7, a0=lane>>3;
        float4 d0=make_float4(0.f,0.f,0.f,0.f), d1=d0;
        #pragma unroll 2
        for (int q=0;q<8;q++){
          float4 c0=*(const float4*)&Ck2[pc][a0*L6+q*4];
          float4 c1=*(const float4*)&Ck2[pc][(a0+8)*L6+q*4];
          float4 p0=*(const float4*)&P[(q*4+0)*L6+qd*4];
          float4 p1=*(const float4*)&P[(q*4+1)*L6+qd*4];
          float4 p2=*(const float4*)&P[(q*4+2)*L6+qd*4];
          float4 p3=*(const float4*)&P[(q*4+3)*L6+qd*4];
          FMA4(d0,c0.x,p0); FMA4(d0,c0.y,p1); FMA4(d0,c0.z,p2); FMA4(d0,c0.w,p3);
          FMA4(d1,c1.x,p0); FMA4(d1,c1.y,p1); FMA4(d1,c1.z,p2); FMA4(d1,c1.w,p3);
        }
        *(float4*)&CPm[a0*L6+qd*4]=d0;
        *(float4*)&CPm[(a0+8)*L6+qd*4]=d1;
        CPT[(qd*4+0)*L0+a0]=d0.x; CPT[(qd*4+1)*L0+a0]=d0.y;
        CPT[(qd*4+2)*L0+a0]=d0.z; CPT[(qd*4+3)*L0+a0]=d0.w;
        CPT[(qd*4+0)*L0+a0+8]=d1.x; CPT[(qd*4+1)*L0+a0+8]=d1.y;
        CPT[(qd*4+2)*L0+a0+8]=d1.z; CPT[(qd*4+3)*L0+a0+8]=d1.w;
      }
      if (lane<16){
        float s=0.f;
        #pragma unroll
        for (int q=0;q<8;q++) s+=dot4(*(const float4*)&Ck2[pc][lane*L6+q*4], *(const float4*)&znew[q*4]);
        rk[lane]=ak[lane]-s;
      }
      {
        int a2=lane>>2, cq=lane&3;
        float s0=0.f,s1=0.f,s2=0.f,s3=0.f;
        #pragma unroll 2
        for (int q=0;q<8;q++){
          float4 cp=*(const float4*)&CPm[a2*L6+q*4];
          s0+=dot4(cp,*(const float4*)&Ck2[pc][(cq*4+0)*L6+q*4]);
          s1+=dot4(cp,*(const float4*)&Ck2[pc][(cq*4+1)*L6+q*4]);
          s2+=dot4(cp,*(const float4*)&Ck2[pc][(cq*4+2)*L6+q*4]);
          s3+=dot4(cp,*(const float4*)&Ck2[pc][(cq*4+3)*L6+q*4]);
        }
        float4 rm=*(const float4*)&Rm[a2*L0+cq*4];
        s0+=rm.x+((a2==cq*4+0)?1e-4f:0.f);
        s1+=rm.y+((a2==cq*4+1)?1e-4f:0.f);
        s2+=rm.z+((a2==cq*4+2)?1e-4f:0.f);
        s3+=rm.w+((a2==cq*4+3)?1e-4f:0.f);
        float4 sv=make_float4(s0,s1,s2,s3);
        *(float4*)&Sm[a2*L0+cq*4]=sv;
        *(float4*)&out[off_S+bt*256+lane*4]=sv;
      }
      {
        int row=lane<16?lane:15;
        float Sr[16], invd[16];
        #pragma unroll
        for (int q=0;q<4;q++){
          float4 v=*(const float4*)&Sm[row*L0+q*4];
          Sr[q*4+0]=v.x; Sr[q*4+1]=v.y; Sr[q*4+2]=v.z; Sr[q*4+3]=v.w;
        }
        #pragma unroll
        for (int c=0;c<16;c++){
          float d=rdlane(Sr[c],c);
          float inv=rsqrtf(d);
          invd[c]=inv;
          float lc=(lane==c)?d*inv:Sr[c]*inv;
          Sr[c]=lc;
          #pragma unroll
          for (int j=c+1;j<16;j++) Sr[j]-=lc*rdlane(lc,j);
        }
        float Li[16], rhs[16];
        #pragma unroll
        for (int r=0;r<16;r++) rhs[r]=(lane==r)?1.f:0.f;
        #pragma unroll
        for (int k=0;k<16;k++){
          float lik=rhs[k]*invd[k];
          Li[k]=lik;
          #pragma unroll
          for (int r=k+1;r<16;r++) rhs[r]-=rdlane(Sr[k],r)*lik;
        }
        if (lane<16){
          #pragma unroll
          for (int r=0;r<16;r++) Linv[r*17+lane]=Li[r];
        }
      }
      if (lane<16){
        float m=mvs2[pc];
        float s=0.f;
        #pragma unroll
        for (int k=0;k<16;k++) s+=Linv[lane*17+k]*(m*rk[k]);
        ys[lane]=s;
      }
      if (lane<16){
        float s=0.f;
        #pragma unroll
        for (int r=0;r<16;r++) s+=Linv[r*17+lane]*ys[r];
        ws[lane]=s;
      }
      if (lane<32){
        float s=znew[lane];
        #pragma unroll
        for (int q=0;q<4;q++)
          s+=dot4(*(const float4*)&CPT[lane*L0+q*4], *(const float4*)&ws[q*4]);
        zloc[lane]=s;
        zc[lane]=s;
        out[off_zf+bt*32+lane]=s;
        out[off_zl+bt*32+lane]=s;
      }
    } else if (wid==1){
      // ghl(t+1) = ghs(t) @ Wh ; uk(t) load
      if (lane<48){
        const int c0=lane*4;
        float4 A0=make_float4(0.f,0.f,0.f,0.f), A1=A0, A2=A0, A3=A0;
        #pragma unroll
        for (int q=0;q<16;q++){
          float4 gv=*(const float4*)&ghs[q*4];
          float4 w0=*(const float4*)(Wh+(size_t)(q*4+0)*192+c0);
          float4 w1=*(const float4*)(Wh+(size_t)(q*4+1)*192+c0);
          float4 w2=*(const float4*)(Wh+(size_t)(q*4+2)*192+c0);
          float4 w3=*(const float4*)(Wh+(size_t)(q*4+3)*192+c0);
          FMA4(A0,gv.x,w0); FMA4(A1,gv.y,w1); FMA4(A2,gv.z,w2); FMA4(A3,gv.w,w3);
        }
        float4 g=make_float4(A0.x+A1.x+A2.x+A3.x, A0.y+A1.y+A2.y+A3.y,
                             A0.z+A1.z+A2.z+A3.z, A0.w+A1.w+A2.w+A3.w);
        *(float4*)&ghl[c0]=g;
      }
      if (lane>=48 && lane<52) uk[lane-48]=u_seq[bt*4+(lane-48)];
    } else if (wid==2){
      if (t>0){
        const size_t bt1=bt-1;
        int row=lane<32?lane:31;
        float trl[32];
        #pragma unroll
        for (int q=0;q<8;q++){
          float4 v=*(const float4*)&T3m[row*L6+q*4];
          trl[q*4+0]=v.x; trl[q*4+1]=v.y; trl[q*4+2]=v.z; trl[q*4+3]=v.w;
        }
        #pragma unroll
        for (int c=0;c<32;c++){
          float d=rdlane(trl[c],c);
          float inv=rsqrtf(d);
          float lc=(lane==c)?d*inv:trl[c]*inv;
          trl[c]=lc;
          #pragma unroll
          for (int j=c+1;j<32;j++) trl[j]-=lc*rdlane(lc,j);
        }
        if (lane<32){
          #pragma unroll
          for (int q=0;q<8;q++){
            float t0=(q*4+0<=lane)?trl[q*4+0]:0.f;
            float t1=(q*4+1<=lane)?trl[q*4+1]:0.f;
            float t2=(q*4+2<=lane)?trl[q*4+2]:0.f;
            float t3=(q*4+3<=lane)?trl[q*4+3]:0.f;
            *(float4*)&out[off_tr+bt1*1024+lane*32+q*4]=make_float4(t0,t1,t2,t3);
          }
        }
      }
    } else {
      // wid==3: blends Ak2[pc]/AkT2[pc] + Bk
      float alr[8];
      float4 a0v=*(const float4*)&alpha8[0], a1v=*(const float4*)&alpha8[4];
      alr[0]=a0v.x; alr[1]=a0v.y; alr[2]=a0v.z; alr[3]=a0v.w;
      alr[4]=a1v.x; alr[5]=a1v.y; alr[6]=a1v.z; alr[7]=a1v.w;
      #pragma unroll
      for (int r=0;r<4;r++){
        int e=lane+64*r; int i=e>>3, qd=e&7;
        float4 acc=make_float4(0.f,0.f,0.f,0.f);
        #pragma unroll
        for (int k=0;k<8;k++){
          float4 av=*(const float4*)&sA[(k*32+i)*L6+qd*4];
          FMA4(acc,alr[k],av);
        }
        *(float4*)&Ak2[pc][i*L6+qd*4]=acc;
        AkT2[pc][(qd*4+0)*L6+i]=acc.x; AkT2[pc][(qd*4+1)*L6+i]=acc.y;
        AkT2[pc][(qd*4+2)*L6+i]=acc.z; AkT2[pc][(qd*4+3)*L6+i]=acc.w;
      }
      #pragma unroll
      for (int r=0;r<2;r++){
        int e=lane+64*r;
        float s=0.f;
        #pragma unroll
        for (int k=0;k<8;k++) s+=alr[k]*sBm[k*128+e];
        Bk[e]=s;
      }
    }
    __syncthreads();
  }

  // ===== Epilogue: tail(T-1) =====
  {
    const size_t btL=(size_t)b*T+(T-1);
    const int pl=(T-1)&1;
    if (wid==1){
      #pragma unroll
      for (int q=0;q<4;q++){
        int e=lane+64*q; int a2=e>>4, b2=e&15;
        float s=0.f;
        #pragma unroll
        for (int k=0;k<16;k++) s+=Linv[k*17+a2]*Linv[k*17+b2];
        Sinv[a2*L0+b2]=s;
      }
      {
        int i0=lane>>2, aq=lane&3;
        float4 k0=make_float4(0.f,0.f,0.f,0.f), k1=k0;
        #pragma unroll
        for (int q=0;q<4;q++){
          float4 ca=*(const float4*)&CPT[i0*L0+q*4];
          float4 cb=*(const float4*)&CPT[(i0+16)*L0+q*4];
          float4 v0=*(const float4*)&Sinv[(q*4+0)*L0+aq*4];
          float4 v1=*(const float4*)&Sinv[(q*4+1)*L0+aq*4];
          float4 v2=*(const float4*)&Sinv[(q*4+2)*L0+aq*4];
          float4 v3=*(const float4*)&Sinv[(q*4+3)*L0+aq*4];
          FMA4(k0,ca.x,v0); FMA4(k0,ca.y,v1); FMA4(k0,ca.z,v2); FMA4(k0,ca.w,v3);
          FMA4(k1,cb.x,v0); FMA4(k1,cb.y,v1); FMA4(k1,cb.z,v2); FMA4(k1,cb.w,v3);
        }
        float m=mvs2[pl];
        k0.x*=m;k0.y*=m;k0.z*=m;k0.w*=m;
        k1.x*=m;k1.y*=m;k1.z*=m;k1.w*=m;
        *(float4*)&Kg[i0*L0+aq*4]=k0;
        *(float4*)&Kg[(i0+16)*L0+aq*4]=k1;
      }
      {
        const int i0=(lane>>3)*4, j0=(lane&7)*4;
        float4 q0=*(const float4*)&P[(i0+0)*L6+j0];
        float4 q1=*(const float4*)&P[(i0+1)*L6+j0];
        float4 q2=*(const float4*)&P[(i0+2)*L6+j0];
        float4 q3=*(const float4*)&P[(i0+3)*L6+j0];
        #pragma unroll
        for (int q=0;q<4;q++){
          float4 a0=*(const float4*)&Kg[(i0+0)*L0+q*4];
          float4 a1=*(const float4*)&Kg[(i0+1)*L0+q*4];
          float4 a2=*(const float4*)&Kg[(i0+2)*L0+q*4];
          float4 a3=*(const float4*)&Kg[(i0+3)*L0+q*4];
          float4 bv;
          bv=*(const float4*)&CPm[(q*4+0)*L6+j0];
          FMA4(q0,-a0.x,bv); FMA4(q1,-a1.x,bv); FMA4(q2,-a2.x,bv); FMA4(q3,-a3.x,bv);
          bv=*(const float4*)&CPm[(q*4+1)*L6+j0];
          FMA4(q0,-a0.y,bv); FMA4(q1,-a1.y,bv); FMA4(q2,-a2.y,bv); FMA4(q3,-a3.y,bv);
          bv=*(const float4*)&CPm[(q*4+2)*L6+j0];
          FMA4(q0,-a0.z,bv); FMA4(q1,-a1.z,bv); FMA4(q2,-a2.z,bv); FMA4(q3,-a3.z,bv);
          bv=*(const float4*)&CPm[(q*4+3)*L6+j0];
          FMA4(q0,-a0.w,bv); FMA4(q1,-a1.w,bv); FMA4(q2,-a2.w,bv); FMA4(q3,-a3.w,bv);
        }
        int d0=i0-j0;
        if (d0>=0&&d0<4){ if(d0==0)q0.x+=1e-3f; else if(d0==1)q0.y+=1e-3f; else if(d0==2)q0.z+=1e-3f; else q0.w+=1e-3f; }
        int d1=i0+1-j0;
        if (d1>=0&&d1<4){ if(d1==0)q1.x+=1e-3f; else if(d1==1)q1.y+=1e-3f; else if(d1==2)q1.z+=1e-3f; else q1.w+=1e-3f; }
        int d2=i0+2-j0;
        if (d2>=0&&d2<4){ if(d2==0)q2.x+=1e-3f; else if(d2==1)q2.y+=1e-3f; else if(d2==2)q2.z+=1e-3f; else q2.w+=1e-3f; }
        int d3=i0+3-j0;
        if (d3>=0&&d3<4){ if(d3==0)q3.x+=1e-3f; else if(d3==1)q3.y+=1e-3f; else if(d3==2)q3.z+=1e-3f; else q3.w+=1e-3f; }
        *(float4*)&T3m[(i0+0)*L6+j0]=q0;
        *(float4*)&T3m[(i0+1)*L6+j0]=q1;
        *(float4*)&T3m[(i0+2)*L6+j0]=q2;
        *(float4*)&T3m[(i0+3)*L6+j0]=q3;
        *(float4*)&out[off_Pf+btL*1024+(i0+0)*32+j0]=q0;
        *(float4*)&out[off_Pf+btL*1024+(i0+1)*32+j0]=q1;
        *(float4*)&out[off_Pf+btL*1024+(i0+2)*32+j0]=q2;
        *(float4*)&out[off_Pf+btL*1024+(i0+3)*32+j0]=q3;
      }
      {
        const int i0=(lane>>3)*4, j0=(lane&7)*4;
        float4 q0=make_float4(0.f,0.f,0.f,0.f), q1=q0, q2=q0, q3=q0;
        #pragma unroll 4
        for (int q=0;q<8;q++){
          float4 a0=*(const float4*)&Ak2[pl][(i0+0)*L6+q*4];
          float4 a1=*(const float4*)&Ak2[pl][(i0+1)*L6+q*4];
          float4 a2=*(const float4*)&Ak2[pl][(i0+2)*L6+q*4];
          float4 a3=*(const float4*)&Ak2[pl][(i0+3)*L6+q*4];
          float4 bv;
          bv=*(const float4*)&T3m[(q*4+0)*L6+j0];
          FMA4(q0,a0.x,bv); FMA4(q1,a1.x,bv); FMA4(q2,a2.x,bv); FMA4(q3,a3.x,bv);
          bv=*(const float4*)&T3m[(q*4+1)*L6+j0];
          FMA4(q0,a0.y,bv); FMA4(q1,a1.y,bv); FMA4(q2,a2.y,bv); FMA4(q3,a3.y,bv);
          bv=*(const float4*)&T3m[(q*4+2)*L6+j0];
          FMA4(q0,a0.z,bv); FMA4(q1,a1.z,bv); FMA4(q2,a2.z,bv); FMA4(q3,a3.z,bv);
          bv=*(const float4*)&T3m[(q*4+3)*L6+j0];
          FMA4(q0,a0.w,bv); FMA4(q1,a1.w,bv); FMA4(q2,a2.w,bv); FMA4(q3,a3.w,bv);
        }
        *(float4*)&T1m[(i0+0)*L6+j0]=q0;
        *(float4*)&T1m[(i0+1)*L6+j0]=q1;
        *(float4*)&T1m[(i0+2)*L6+j0]=q2;
        *(float4*)&T1m[(i0+3)*L6+j0]=q3;
      }
      {
        const int i0=(lane>>3)*4, j0=(lane&7)*4;
        float4 q0=*(const float4*)&Qm[(i0+0)*L6+j0];
        float4 q1=*(const float4*)&Qm[(i0+1)*L6+j0];
        float4 q2=*(const float4*)&Qm[(i0+2)*L6+j0];
        float4 q3=*(const float4*)&Qm[(i0+3)*L6+j0];
        int d0=i0-j0;
        if (d0>=0&&d0<4){ if(d0==0)q0.x+=1e-3f; else if(d0==1)q0.y+=1e-3f; else if(d0==2)q0.z+=1e-3f; else q0.w+=1e-3f; }
        int d1=i0+1-j0;
        if (d1>=0&&d1<4){ if(d1==0)q1.x+=1e-3f; else if(d1==1)q1.y+=1e-3f; else if(d1==2)q1.z+=1e-3f; else q1.w+=1e-3f; }
        int d2=i0+2-j0;
        if (d2>=0&&d2<4){ if(d2==0)q2.x+=1e-3f; else if(d2==1)q2.y+=1e-3f; else if(d2==2)q2.z+=1e-3f; else q2.w+=1e-3f; }
        int d3=i0+3-j0;
        if (d3>=0&&d3<4){ if(d3==0)q3.x+=1e-3f; else if(d3==1)q3.y+=1e-3f; else if(d3==2)q3.z+=1e-3f; else q3.w+=1e-3f; }
        #pragma unroll 4
        for (int q=0;q<8;q++){
          float4 a0=*(const float4*)&T1m[(i0+0)*L6+q*4];
          float4 a1=*(const float4*)&T1m[(i0+1)*L6+q*4];
          float4 a2=*(const float4*)&T1m[(i0+2)*L6+q*4];
          float4 a3=*(const float4*)&T1m[(i0+3)*L6+q*4];
          float4 bv;
          bv=*(const float4*)&AkT2[pl][(q*4+0)*L6+j0];
          FMA4(q0,a0.x,bv); FMA4(q1,a1.x,bv); FMA4(q2,a2.x,bv); FMA4(q3,a3.x,bv);
          bv=*(const float4*)&AkT2[pl][(q*4+1)*L6+j0];
          FMA4(q0,a0.y,bv); FMA4(q1,a1.y,bv); FMA4(q2,a2.y,bv); FMA4(q3,a3.y,bv);
          bv=*(const float4*)&AkT2[pl][(q*4+2)*L6+j0];
          FMA4(q0,a0.z,bv); FMA4(q1,a1.z,bv); FMA4(q2,a2.z,bv); FMA4(q3,a3.z,bv);
          bv=*(const float4*)&AkT2[pl][(q*4+3)*L6+j0];
          FMA4(q0,a0.w,bv); FMA4(q1,a1.w,bv); FMA4(q2,a2.w,bv); FMA4(q3,a3.w,bv);
        }
        *(float4*)&out[off_Pp+btL*1024+(i0+0)*32+j0]=q0;
        *(float4*)&out[off_Pp+btL*1024+(i0+1)*32+j0]=q1;
        *(float4*)&out[off_Pp+btL*1024+(i0+2)*32+j0]=q2;
        *(float4*)&out[off_Pp+btL*1024+(i0+3)*32+j0]=q3;
      }
    } else if (wid==2){
      float4 zq[8];
      #pragma unroll
      for (int q=0;q<8;q++) zq[q]=*(const float4*)&zc[q*4];
      if (lane<32){
        float s=0.f;
        #pragma unroll
        for (int q=0;q<8;q++) s+=dot4(*(const float4*)&Ak2[pl][lane*L6+q*4], zq[q]);
        float4 bk=*(const float4*)&Bk[lane*4];
        float4 u4=*(const float4*)&uk[0];
        s+=dot4(bk,u4);
        zpred[lane]=s;
        out[off_zp+btL*32+lane]=s;
      }
      if (lane>=32 && lane<48){
        int a=lane-32;
        float s=0.f;
        #pragma unroll
        for (int q=0;q<8;q++) s+=dot4(*(const float4*)&Ck2[pl][a*L6+q*4], zq[q]);
        out[off_af+btL*16+a]=s;
      }
      if (lane<16){
        float s=0.f;
        #pragma unroll
        for (int q=0;q<8;q++)
          s+=dot4(*(const float4*)&Ck2[pl][lane*L6+q*4], *(const float4*)&zpred[q*4]);
        out[off_ap+btL*16+lane]=s;
      }
    }
    __syncthreads();
    if (wid==2){
      int row=lane<32?lane:31;
      float trl[32];
      #pragma unroll
      for (int q=0;q<8;q++){
        float4 v=*(const float4*)&T3m[row*L6+q*4];
        trl[q*4+0]=v.x; trl[q*4+1]=v.y; trl[q*4+2]=v.z; trl[q*4+3]=v.w;
      }
      #pragma unroll
      for (int c=0;c<32;c++){
        float d=rdlane(trl[c],c);
        float inv=rsqrtf(d);
        float lc=(lane==c)?d*inv:trl[c]*inv;
        trl[c]=lc;
        #pragma unroll
        for (int j=c+1;j<32;j++) trl[j]-=lc*rdlane(lc,j);
      }
      if (lane<32){
        #pragma unroll
        for (int q=0;q<8;q++){
          float t0=(q*4+0<=lane)?trl[q*4+0]:0.f;
          float t1=(q*4+1<=lane)?trl[q*4+1]:0.f;
          float t2=(q*4+2<=lane)?trl[q*4+2]:0.f;
          float t3=(q*4+3<=lane)?trl[q*4+3]:0.f;
          *(float4*)&out[off_tr+btL*1024+lane*32+q*4]=make_float4(t0,t1,t2,t3);
        }
      }
    }
  }
}

extern "C" void kernel_launch(void* const* d_in, const int* in_sizes, int n_in,
                              void* d_out, int out_size, void* d_ws, size_t ws_size,
                              hipStream_t stream) {
  kf_fwd<<<128, NT, 0, stream>>>(
    (const float*)d_in[0],  // a_seq
    (const float*)d_in[1],  // h_obs
    (const float*)d_in[2],  // A_matrices
    (const float*)d_in[3],  // C_matrices
    (const float*)d_in[4],  // B_matrices
    (const float*)d_in[5],  // u_seq
    (const float*)d_in[6],  // mask
    (const float*)d_in[7],  // P_0
    (const float*)d_in[8],  // mat_Q
    (const float*)d_in[9],  // mat_R
    (const float*)d_in[10], // gru_Wx
    (const float*)d_in[11], // gru_Wh
    (const float*)d_in[12], // gru_b
    (const float*)d_in[13], // out_W
    (const float*)d_in[14], // out_b
    (float*)d_out);
}